// Round 8
// baseline (113.468 us; speedup 1.0000x reference)
//
#include <hip/hip_runtime.h>

namespace {
constexpr int PB = 6 * 256;  // 1536 independent (l,n) problems
constexpr int Q = 64;
constexpr int C = 256;
constexpr float EPS_DEN = 1e-7f;
constexpr float EPS_SQRT = 1e-12f;
constexpr int GT_FLOATS = Q * Q;  // 4096 per problem (transposed-packed)
constexpr int AUX_FLOATS = 256;   // xc0[64][2] | x2[64] | c2 partials[8]

typedef __attribute__((ext_vector_type(8))) short bf16x8;
typedef __attribute__((ext_vector_type(4))) float f32x4;

// DPP row rotate-add (VALU pipe). Proven R1/R5.
template <int CTRL>
__device__ __forceinline__ float ror_add(float v) {
  int r = __builtin_amdgcn_mov_dpp(__float_as_int(v), CTRL, 0xF, 0xF, true);
  return v + __int_as_float(r);
}

// Canonical GCN wave64 DPP reduction; all-lane result via readlane 63.
// Proven R5-R7 (passed).
__device__ __forceinline__ float wave_total(float v) {
  v = ror_add<0x121>(v);  // row_ror:1
  v = ror_add<0x122>(v);  // row_ror:2
  v = ror_add<0x124>(v);  // row_ror:4
  v = ror_add<0x128>(v);  // row_ror:8
  {
    int t = __builtin_amdgcn_update_dpp(0, __float_as_int(v), 0x142, 0xA, 0xF,
                                        true);  // ROW_BCAST15
    v = v + __int_as_float(t);
  }
  {
    int t = __builtin_amdgcn_update_dpp(0, __float_as_int(v), 0x143, 0xC, 0xF,
                                        true);  // ROW_BCAST31
    v = v + __int_as_float(t);
  }
  return __int_as_float(__builtin_amdgcn_readlane(__float_as_int(v), 63));
}

__device__ __forceinline__ ushort bf16_rne(float x) {
  uint u = __float_as_uint(x);
  return (ushort)((u + 0x7FFFu + ((u >> 16) & 1u)) >> 16);
}
__device__ __forceinline__ float bf16_up(ushort h) {
  return __uint_as_float((uint)h << 16);
}
}  // namespace

// -------- kernel 1: G = H H^T via bf16-split MFMA; x2=diag(G); xc0; c2_0
// __launch_bounds__(256,2): R6 showed (256,4) squeezes VGPR 124->64 and
// spills acc to scratch (+23 MB WRITE, 27->68 us). LDS caps blocks/CU anyway.
__global__ __launch_bounds__(256, 2) void k1_gram(
    const float* __restrict__ hs, const float* __restrict__ cen,
    float* __restrict__ ws) {
  const int prob = blockIdx.x;
  const int tid = threadIdx.x;
  const int lane = tid & 63, w = tid >> 6;
  const int li = lane & 15, lk = lane >> 4;

  __shared__ __align__(16) ushort Hh[64 * 128];  // bf16 hi plane (one C-half)
  __shared__ __align__(16) ushort Hl[64 * 128];  // bf16 lo plane
  __shared__ __align__(16) ushort Ch[2 * 256];   // cen hi (full C, linear)
  __shared__ __align__(16) ushort Cl[2 * 256];   // cen lo

  const float4* hsg4 = (const float4*)(hs + (size_t)prob * Q * C);
  float* gtp = ws + (size_t)prob * GT_FLOATS;
  float* aux = ws + (size_t)PB * GT_FLOATS + (size_t)prob * AUX_FLOATS;

  f32x4 acc[4] = {{0.f, 0.f, 0.f, 0.f},
                  {0.f, 0.f, 0.f, 0.f},
                  {0.f, 0.f, 0.f, 0.f},
                  {0.f, 0.f, 0.f, 0.f}};
  f32x4 accX = {0.f, 0.f, 0.f, 0.f};
  const int rA = 16 * w + li;
  const int swz = (li & 7) << 4;

#pragma unroll 1
  for (int half = 0; half < 2; ++half) {
#pragma unroll
    for (int i = 0; i < 8; ++i) {
      const int c = i * 256 + tid;  // 2048 chunks = 64 rows x 32 col4
      const int r = c >> 5, col4 = c & 31;
      float4 v = hsg4[r * 64 + half * 32 + col4];
      ushort h0 = bf16_rne(v.x), h1 = bf16_rne(v.y), h2 = bf16_rne(v.z),
             h3 = bf16_rne(v.w);
      ushort l0 = bf16_rne(v.x - bf16_up(h0));
      ushort l1 = bf16_rne(v.y - bf16_up(h1));
      ushort l2 = bf16_rne(v.z - bf16_up(h2));
      ushort l3 = bf16_rne(v.w - bf16_up(h3));
      const int boff = (col4 * 8) ^ ((r & 7) << 4);
      const int idx = r * 128 + (boff >> 1);
      *(ushort4*)&Hh[idx] = make_ushort4(h0, h1, h2, h3);
      *(ushort4*)&Hl[idx] = make_ushort4(l0, l1, l2, l3);
    }
    if (half == 0) {
      if (tid < 128) {
        const float4* cg4 = (const float4*)(cen + (size_t)prob * 2 * C);
        float4 v = cg4[tid];
        ushort h0 = bf16_rne(v.x), h1 = bf16_rne(v.y), h2 = bf16_rne(v.z),
               h3 = bf16_rne(v.w);
        ushort l0 = bf16_rne(v.x - bf16_up(h0));
        ushort l1 = bf16_rne(v.y - bf16_up(h1));
        ushort l2 = bf16_rne(v.z - bf16_up(h2));
        ushort l3 = bf16_rne(v.w - bf16_up(h3));
        const int idx = (tid >> 6) * 256 + (tid & 63) * 4;
        *(ushort4*)&Ch[idx] = make_ushort4(h0, h1, h2, h3);
        *(ushort4*)&Cl[idx] = make_ushort4(l0, l1, l2, l3);
      }
      float c0v = cen[(size_t)prob * 2 * C + tid];
      float c1v = cen[(size_t)prob * 2 * C + C + tid];
      float p0 = wave_total(c0v * c0v);
      float p1 = wave_total(c1v * c1v);
      if (lane == 0) {
        aux[192 + w] = p0;
        aux[196 + w] = p1;
      }
    }
    __syncthreads();

#pragma unroll
    for (int kk2 = 0; kk2 < 4; ++kk2) {
      const int kk = half * 4 + kk2;
      const int byteA = (kk2 * 64 + lk * 16) ^ swz;
      const int offA = byteA >> 1;
      bf16x8 ah = *(const bf16x8*)&Hh[rA * 128 + offA];
      bf16x8 al = *(const bf16x8*)&Hl[rA * 128 + offA];
      bf16x8 cbh = {0, 0, 0, 0, 0, 0, 0, 0};
      bf16x8 cbl = {0, 0, 0, 0, 0, 0, 0, 0};
      if (li < 2) {
        const int cidx = li * 256 + kk * 32 + lk * 8;
        cbh = *(const bf16x8*)&Ch[cidx];
        cbl = *(const bf16x8*)&Cl[cidx];
      }
      accX = __builtin_amdgcn_mfma_f32_16x16x32_bf16(ah, cbh, accX, 0, 0, 0);
      accX = __builtin_amdgcn_mfma_f32_16x16x32_bf16(ah, cbl, accX, 0, 0, 0);
      accX = __builtin_amdgcn_mfma_f32_16x16x32_bf16(al, cbh, accX, 0, 0, 0);
#pragma unroll
      for (int tj = 0; tj < 4; ++tj) {
        if (tj < w) continue;  // wave-uniform skip (symmetry)
        const int rB = 16 * tj + li;
        bf16x8 bh = *(const bf16x8*)&Hh[rB * 128 + offA];
        bf16x8 bl = *(const bf16x8*)&Hl[rB * 128 + offA];
        acc[tj] =
            __builtin_amdgcn_mfma_f32_16x16x32_bf16(ah, bh, acc[tj], 0, 0, 0);
        acc[tj] =
            __builtin_amdgcn_mfma_f32_16x16x32_bf16(ah, bl, acc[tj], 0, 0, 0);
        acc[tj] =
            __builtin_amdgcn_mfma_f32_16x16x32_bf16(al, bh, acc[tj], 0, 0, 0);
      }
    }
    __syncthreads();
  }

#pragma unroll
  for (int tj = 0; tj < 4; ++tj) {
    if (tj < w) continue;
#pragma unroll
    for (int r = 0; r < 4; ++r) {
      const float v = acc[tj][r];
      const int row = 16 * w + lk * 4 + r;
      const int col = 16 * tj + li;
      gtp[(col >> 2) * 256 + row * 4 + (col & 3)] = v;
      if (tj > w) gtp[(row >> 2) * 256 + col * 4 + (row & 3)] = v;
      if (row == col) aux[128 + row] = v;
    }
  }
  if (li < 2) {
#pragma unroll
    for (int r = 0; r < 4; ++r) {
      const int q = 16 * w + lk * 4 + r;
      aux[q * 2 + li] = accX[r];
    }
  }
}

// -------- kernel 2: 64 EM iterations, TWO problems per wave (ILP-2).
// R7 measured: wall = 64 x per-iter serial latency (~2400 cyc) — latency-
// bound, occupancy-irrelevant. Two independent problems' chains interleave
// in one wave, hiding each other's LDS/MFMA/trans latency. Per-problem math
// bit-identical to R7.
__global__ __launch_bounds__(64, 1) void k2_iter(const float* __restrict__ hs,
                                                 const float* __restrict__ ws,
                                                 float* __restrict__ out) {
  const int pb = blockIdx.x * 2;  // problems pb, pb+1
  const int lane = threadIdx.x;   // = q
  const int li = lane & 15, lk = lane >> 4;

  __shared__ __align__(16) ushort Ah[2][2][64];  // [prob][cluster][q] hi
  __shared__ __align__(16) ushort Al[2][2][64];  // lo plane
  __shared__ __align__(16) float m_s[2][2][64];  // [prob][cluster][q]
  __shared__ __align__(16) float a_s[2][2 * Q];  // final a (epilogue)

  // ---- G -> A-fragments (bf16 split) for both problems
  bf16x8 Gh[2][4][2], Gl[2][4][2];
#pragma unroll
  for (int P = 0; P < 2; ++P) {
    const float4* gt4 = (const float4*)(ws + (size_t)(pb + P) * GT_FLOATS);
#pragma unroll
    for (int t = 0; t < 4; ++t) {
#pragma unroll
      for (int kk = 0; kk < 2; ++kk) {
        const int cj = 8 * kk + 2 * lk;
        float4 ga = gt4[cj * 64 + 16 * t + li];
        float4 gb = gt4[(cj + 1) * 64 + 16 * t + li];
        float g[8] = {ga.x, ga.y, ga.z, ga.w, gb.x, gb.y, gb.z, gb.w};
        bf16x8 hh, ll;
#pragma unroll
        for (int j = 0; j < 8; ++j) {
          ushort h = bf16_rne(g[j]);
          hh[j] = (short)h;
          ll[j] = (short)bf16_rne(g[j] - bf16_up(h));
        }
        Gh[P][t][kk] = hh;
        Gl[P][t][kk] = ll;
      }
    }
  }

  float x2[2], xc0[2], xc1[2], c20[2], c21[2], a0[2], a1[2];
#pragma unroll
  for (int P = 0; P < 2; ++P) {
    const float* aux =
        ws + (size_t)PB * GT_FLOATS + (size_t)(pb + P) * AUX_FLOATS;
    x2[P] = aux[128 + lane];
    xc0[P] = aux[lane * 2 + 0];
    xc1[P] = aux[lane * 2 + 1];
    c20[P] = aux[192] + aux[193] + aux[194] + aux[195];
    c21[P] = aux[196] + aux[197] + aux[198] + aux[199];
    a0[P] = 0.f;
    a1[P] = 0.f;
  }

  const int cl = li & 1;  // cluster this lane's B-frag serves

#pragma unroll 1
  for (int t = 0; t < Q; ++t) {
#pragma unroll
    for (int P = 0; P < 2; ++P) {
      float d0 = fmaxf(x2[P] + c20[P] - 2.f * xc0[P], EPS_SQRT);
      float d1 = fmaxf(x2[P] + c21[P] - 2.f * xc1[P], EPS_SQRT);
      float t0 = __builtin_amdgcn_sqrtf(d0), t1 = __builtin_amdgcn_sqrtf(d1);
      float mn = fminf(t0, t1);
      float e0 = __expf(mn - t0), e1 = __expf(mn - t1);
      float inv = __builtin_amdgcn_rcpf(e0 + e1);
      a0[P] = e0 * inv;
      a1[P] = e1 * inv;
    }
    if (t == Q - 1) break;

    // ---- a -> bf16-split SoA in LDS (8 ds_write_b16)
#pragma unroll
    for (int P = 0; P < 2; ++P) {
      ushort h0 = bf16_rne(a0[P]);
      ushort l0 = bf16_rne(a0[P] - bf16_up(h0));
      ushort h1 = bf16_rne(a1[P]);
      ushort l1 = bf16_rne(a1[P] - bf16_up(h1));
      Ah[P][0][lane] = h0;
      Al[P][0][lane] = l0;
      Ah[P][1][lane] = h1;
      Al[P][1][lane] = l1;
    }
    // den reductions (4 independent DPP chains) overlap LDS write latency
    float den0[2], den1[2];
#pragma unroll
    for (int P = 0; P < 2; ++P) {
      den0[P] = wave_total(a0[P]);
      den1[P] = wave_total(a1[P]);
    }
    __syncthreads();

    // ---- B-fragments of a (8 ds_read_b128)
    bf16x8 bh[2][2], bl[2][2];
#pragma unroll
    for (int P = 0; P < 2; ++P) {
#pragma unroll
      for (int kk = 0; kk < 2; ++kk) {
        bh[P][kk] = *(const bf16x8*)&Ah[P][cl][kk * 32 + lk * 8];
        bl[P][kk] = *(const bf16x8*)&Al[P][cl][kk * 32 + lk * 8];
      }
    }
    // ---- m = G.a : 48 MFMA, 8 independent dep-chains of 6
    f32x4 acc[2][4];
#pragma unroll
    for (int P = 0; P < 2; ++P)
#pragma unroll
      for (int tt = 0; tt < 4; ++tt) acc[P][tt] = {0.f, 0.f, 0.f, 0.f};
#pragma unroll
    for (int tt = 0; tt < 4; ++tt) {
#pragma unroll
      for (int P = 0; P < 2; ++P) {
#pragma unroll
        for (int kk = 0; kk < 2; ++kk) {
          acc[P][tt] = __builtin_amdgcn_mfma_f32_16x16x32_bf16(
              Gh[P][tt][kk], bh[P][kk], acc[P][tt], 0, 0, 0);
          acc[P][tt] = __builtin_amdgcn_mfma_f32_16x16x32_bf16(
              Gh[P][tt][kk], bl[P][kk], acc[P][tt], 0, 0, 0);
          acc[P][tt] = __builtin_amdgcn_mfma_f32_16x16x32_bf16(
              Gl[P][tt][kk], bh[P][kk], acc[P][tt], 0, 0, 0);
        }
      }
    }
    // ---- C-frag (col=li=cluster, row=16t+lk*4+r) -> m_s
    if (li < 2) {
#pragma unroll
      for (int P = 0; P < 2; ++P)
#pragma unroll
        for (int tt = 0; tt < 4; ++tt)
          *(float4*)&m_s[P][li][16 * tt + lk * 4] = make_float4(
              acc[P][tt][0], acc[P][tt][1], acc[P][tt][2], acc[P][tt][3]);
    }
    __syncthreads();

    float m0[2], m1[2], s0[2], s1[2];
#pragma unroll
    for (int P = 0; P < 2; ++P) {
      m0[P] = m_s[P][0][lane];
      m1[P] = m_s[P][1][lane];
    }
#pragma unroll
    for (int P = 0; P < 2; ++P) {
      s0[P] = wave_total(a0[P] * m0[P]);  // = |num_0|^2
      s1[P] = wave_total(a1[P] * m1[P]);
    }
#pragma unroll
    for (int P = 0; P < 2; ++P) {
      float i0 = __builtin_amdgcn_rcpf(den0[P] + EPS_DEN);
      float i1 = __builtin_amdgcn_rcpf(den1[P] + EPS_DEN);
      xc0[P] = m0[P] * i0;
      xc1[P] = m1[P] * i1;
      c20[P] = s0[P] * i0 * i0;
      c21[P] = s1[P] * i1 * i1;
    }
  }

  // ---- epilogue: centers = (a^T hs)/(den+eps); write assignment
#pragma unroll
  for (int P = 0; P < 2; ++P)
    *(float2*)&a_s[P][lane * 2] = make_float2(a0[P], a1[P]);
  float den0[2], den1[2];
#pragma unroll
  for (int P = 0; P < 2; ++P) {
    den0[P] = wave_total(a0[P]);
    den1[P] = wave_total(a1[P]);
  }
  __syncthreads();

  float4 n0[2], n1[2];
#pragma unroll
  for (int P = 0; P < 2; ++P) {
    n0[P] = make_float4(0.f, 0.f, 0.f, 0.f);
    n1[P] = make_float4(0.f, 0.f, 0.f, 0.f);
  }
#pragma unroll 4
  for (int q2 = 0; q2 < Q; ++q2) {
#pragma unroll
    for (int P = 0; P < 2; ++P) {
      const float4* hb4 = (const float4*)(hs + (size_t)(pb + P) * Q * C);
      float4 h = hb4[q2 * 64 + lane];
      float2 aq = *(const float2*)&a_s[P][q2 * 2];
      n0[P].x = fmaf(aq.x, h.x, n0[P].x);
      n0[P].y = fmaf(aq.x, h.y, n0[P].y);
      n0[P].z = fmaf(aq.x, h.z, n0[P].z);
      n0[P].w = fmaf(aq.x, h.w, n0[P].w);
      n1[P].x = fmaf(aq.y, h.x, n1[P].x);
      n1[P].y = fmaf(aq.y, h.y, n1[P].y);
      n1[P].z = fmaf(aq.y, h.z, n1[P].z);
      n1[P].w = fmaf(aq.y, h.w, n1[P].w);
    }
  }
#pragma unroll
  for (int P = 0; P < 2; ++P) {
    float i0 = __builtin_amdgcn_rcpf(den0[P] + EPS_DEN);
    float i1 = __builtin_amdgcn_rcpf(den1[P] + EPS_DEN);
    float4* outc4 = (float4*)(out + (size_t)(pb + P) * 2 * C);
    outc4[lane] =
        make_float4(n0[P].x * i0, n0[P].y * i0, n0[P].z * i0, n0[P].w * i0);
    outc4[64 + lane] =
        make_float4(n1[P].x * i1, n1[P].y * i1, n1[P].z * i1, n1[P].w * i1);
    float* outa = out + (size_t)PB * 2 * C + (size_t)(pb + P) * Q * 2;
    *(float2*)&outa[lane * 2] = make_float2(a0[P], a1[P]);
  }
}

extern "C" void kernel_launch(void* const* d_in, const int* in_sizes, int n_in,
                              void* d_out, int out_size, void* d_ws,
                              size_t ws_size, hipStream_t stream) {
  const float* hs = (const float*)d_in[0];
  const float* cen = (const float*)d_in[1];
  float* out = (float*)d_out;
  float* ws = (float*)d_ws;  // needs PB*(4096+256)*4 B ~= 26.8 MB
  hipLaunchKernelGGL(k1_gram, dim3(PB), dim3(256), 0, stream, hs, cen, ws);
  hipLaunchKernelGGL(k2_iter, dim3(PB / 2), dim3(64), 0, stream, hs, ws, out);
}

// Round 9
// 90.073 us; speedup vs baseline: 1.2597x; 1.2597x over previous
//
#include <hip/hip_runtime.h>

namespace {
constexpr int PB = 6 * 256;  // 1536 independent (l,n) problems
constexpr int Q = 64;
constexpr int C = 256;
constexpr float EPS_DEN = 1e-7f;
constexpr float EPS_SQRT = 1e-12f;
constexpr int GT_FLOATS = Q * Q;  // 4096 per problem (transposed-packed)
constexpr int AUX_FLOATS = 256;   // xc0[64][2] | x2[64] | c2 partials[8]

typedef __attribute__((ext_vector_type(8))) short bf16x8;
typedef __attribute__((ext_vector_type(4))) float f32x4;

// DPP row rotate-add (VALU pipe). Proven R1/R5.
template <int CTRL>
__device__ __forceinline__ float ror_add(float v) {
  int r = __builtin_amdgcn_mov_dpp(__float_as_int(v), CTRL, 0xF, 0xF, true);
  return v + __int_as_float(r);
}

// Canonical GCN wave64 DPP reduction; all-lane result via readlane 63.
// Proven R5-R7 (passed).
__device__ __forceinline__ float wave_total(float v) {
  v = ror_add<0x121>(v);  // row_ror:1
  v = ror_add<0x122>(v);  // row_ror:2
  v = ror_add<0x124>(v);  // row_ror:4
  v = ror_add<0x128>(v);  // row_ror:8
  {
    int t = __builtin_amdgcn_update_dpp(0, __float_as_int(v), 0x142, 0xA, 0xF,
                                        true);  // ROW_BCAST15
    v = v + __int_as_float(t);
  }
  {
    int t = __builtin_amdgcn_update_dpp(0, __float_as_int(v), 0x143, 0xC, 0xF,
                                        true);  // ROW_BCAST31
    v = v + __int_as_float(t);
  }
  return __int_as_float(__builtin_amdgcn_readlane(__float_as_int(v), 63));
}

__device__ __forceinline__ ushort bf16_rne(float x) {
  uint u = __float_as_uint(x);
  return (ushort)((u + 0x7FFFu + ((u >> 16) & 1u)) >> 16);
}
__device__ __forceinline__ float bf16_up(ushort h) {
  return __uint_as_float((uint)h << 16);
}

// Compiler-only fence: keeps LDS write->read program order without s_barrier.
// Valid for SINGLE-WAVE blocks: the DS pipe processes a wave's ops in order.
__device__ __forceinline__ void wave_fence() { asm volatile("" ::: "memory"); }
}  // namespace

// -------- kernel 1: G = H H^T via bf16-split MFMA; x2=diag(G); xc0; c2_0
// __launch_bounds__(256,2): R6 showed (256,4) squeezes VGPR 124->64 and
// spills acc to scratch (+23 MB WRITE, 27->68 us). LDS caps blocks/CU anyway.
__global__ __launch_bounds__(256, 2) void k1_gram(
    const float* __restrict__ hs, const float* __restrict__ cen,
    float* __restrict__ ws) {
  const int prob = blockIdx.x;
  const int tid = threadIdx.x;
  const int lane = tid & 63, w = tid >> 6;
  const int li = lane & 15, lk = lane >> 4;

  __shared__ __align__(16) ushort Hh[64 * 128];  // bf16 hi plane (one C-half)
  __shared__ __align__(16) ushort Hl[64 * 128];  // bf16 lo plane
  __shared__ __align__(16) ushort Ch[2 * 256];   // cen hi (full C, linear)
  __shared__ __align__(16) ushort Cl[2 * 256];   // cen lo

  const float4* hsg4 = (const float4*)(hs + (size_t)prob * Q * C);
  float* gtp = ws + (size_t)prob * GT_FLOATS;
  float* aux = ws + (size_t)PB * GT_FLOATS + (size_t)prob * AUX_FLOATS;

  f32x4 acc[4] = {{0.f, 0.f, 0.f, 0.f},
                  {0.f, 0.f, 0.f, 0.f},
                  {0.f, 0.f, 0.f, 0.f},
                  {0.f, 0.f, 0.f, 0.f}};
  f32x4 accX = {0.f, 0.f, 0.f, 0.f};
  const int rA = 16 * w + li;
  const int swz = (li & 7) << 4;

#pragma unroll 1
  for (int half = 0; half < 2; ++half) {
#pragma unroll
    for (int i = 0; i < 8; ++i) {
      const int c = i * 256 + tid;  // 2048 chunks = 64 rows x 32 col4
      const int r = c >> 5, col4 = c & 31;
      float4 v = hsg4[r * 64 + half * 32 + col4];
      ushort h0 = bf16_rne(v.x), h1 = bf16_rne(v.y), h2 = bf16_rne(v.z),
             h3 = bf16_rne(v.w);
      ushort l0 = bf16_rne(v.x - bf16_up(h0));
      ushort l1 = bf16_rne(v.y - bf16_up(h1));
      ushort l2 = bf16_rne(v.z - bf16_up(h2));
      ushort l3 = bf16_rne(v.w - bf16_up(h3));
      const int boff = (col4 * 8) ^ ((r & 7) << 4);
      const int idx = r * 128 + (boff >> 1);
      *(ushort4*)&Hh[idx] = make_ushort4(h0, h1, h2, h3);
      *(ushort4*)&Hl[idx] = make_ushort4(l0, l1, l2, l3);
    }
    if (half == 0) {
      if (tid < 128) {
        const float4* cg4 = (const float4*)(cen + (size_t)prob * 2 * C);
        float4 v = cg4[tid];
        ushort h0 = bf16_rne(v.x), h1 = bf16_rne(v.y), h2 = bf16_rne(v.z),
               h3 = bf16_rne(v.w);
        ushort l0 = bf16_rne(v.x - bf16_up(h0));
        ushort l1 = bf16_rne(v.y - bf16_up(h1));
        ushort l2 = bf16_rne(v.z - bf16_up(h2));
        ushort l3 = bf16_rne(v.w - bf16_up(h3));
        const int idx = (tid >> 6) * 256 + (tid & 63) * 4;
        *(ushort4*)&Ch[idx] = make_ushort4(h0, h1, h2, h3);
        *(ushort4*)&Cl[idx] = make_ushort4(l0, l1, l2, l3);
      }
      float c0v = cen[(size_t)prob * 2 * C + tid];
      float c1v = cen[(size_t)prob * 2 * C + C + tid];
      float p0 = wave_total(c0v * c0v);
      float p1 = wave_total(c1v * c1v);
      if (lane == 0) {
        aux[192 + w] = p0;
        aux[196 + w] = p1;
      }
    }
    __syncthreads();

#pragma unroll
    for (int kk2 = 0; kk2 < 4; ++kk2) {
      const int kk = half * 4 + kk2;
      const int byteA = (kk2 * 64 + lk * 16) ^ swz;
      const int offA = byteA >> 1;
      bf16x8 ah = *(const bf16x8*)&Hh[rA * 128 + offA];
      bf16x8 al = *(const bf16x8*)&Hl[rA * 128 + offA];
      bf16x8 cbh = {0, 0, 0, 0, 0, 0, 0, 0};
      bf16x8 cbl = {0, 0, 0, 0, 0, 0, 0, 0};
      if (li < 2) {
        const int cidx = li * 256 + kk * 32 + lk * 8;
        cbh = *(const bf16x8*)&Ch[cidx];
        cbl = *(const bf16x8*)&Cl[cidx];
      }
      accX = __builtin_amdgcn_mfma_f32_16x16x32_bf16(ah, cbh, accX, 0, 0, 0);
      accX = __builtin_amdgcn_mfma_f32_16x16x32_bf16(ah, cbl, accX, 0, 0, 0);
      accX = __builtin_amdgcn_mfma_f32_16x16x32_bf16(al, cbh, accX, 0, 0, 0);
#pragma unroll
      for (int tj = 0; tj < 4; ++tj) {
        if (tj < w) continue;  // wave-uniform skip (symmetry)
        const int rB = 16 * tj + li;
        bf16x8 bh = *(const bf16x8*)&Hh[rB * 128 + offA];
        bf16x8 bl = *(const bf16x8*)&Hl[rB * 128 + offA];
        acc[tj] =
            __builtin_amdgcn_mfma_f32_16x16x32_bf16(ah, bh, acc[tj], 0, 0, 0);
        acc[tj] =
            __builtin_amdgcn_mfma_f32_16x16x32_bf16(ah, bl, acc[tj], 0, 0, 0);
        acc[tj] =
            __builtin_amdgcn_mfma_f32_16x16x32_bf16(al, bh, acc[tj], 0, 0, 0);
      }
    }
    __syncthreads();
  }

#pragma unroll
  for (int tj = 0; tj < 4; ++tj) {
    if (tj < w) continue;
#pragma unroll
    for (int r = 0; r < 4; ++r) {
      const float v = acc[tj][r];
      const int row = 16 * w + lk * 4 + r;
      const int col = 16 * tj + li;
      gtp[(col >> 2) * 256 + row * 4 + (col & 3)] = v;
      if (tj > w) gtp[(row >> 2) * 256 + col * 4 + (row & 3)] = v;
      if (row == col) aux[128 + row] = v;
    }
  }
  if (li < 2) {
#pragma unroll
    for (int r = 0; r < 4; ++r) {
      const int q = 16 * w + lk * 4 + r;
      aux[q * 2 + li] = accX[r];
    }
  }
}

// -------- kernel 2: 64 EM iterations, 1 wave/problem (R7 structure).
// R9 change: 1-wave block => s_barrier is pure overhead (DS pipe is in-order
// per wave); replaced with compiler-only fences. R8 showed ILP-2 regresses
// (iteration is ~half issue-bound), so back to 1 problem/wave.
__global__ __launch_bounds__(64, 2) void k2_iter(const float* __restrict__ hs,
                                                 const float* __restrict__ ws,
                                                 float* __restrict__ out) {
  const int prob = blockIdx.x;
  const int lane = threadIdx.x;  // = q
  const int li = lane & 15, lk = lane >> 4;

  __shared__ __align__(16) ushort Ah[2][64];  // a hi-plane, SoA per cluster
  __shared__ __align__(16) ushort Al[2][64];  // a lo-plane
  __shared__ __align__(16) float m_s[2][64];  // m = G.a, SoA per cluster
  __shared__ __align__(16) float a_s[2 * Q];  // final a (epilogue)

  const float4* gt4 = (const float4*)(ws + (size_t)prob * GT_FLOATS);
  const float* aux = ws + (size_t)PB * GT_FLOATS + (size_t)prob * AUX_FLOATS;

  // ---- G -> A-fragments (bf16 split), row = 16t+li, k = kk*32+lk*8+j.
  bf16x8 Gh[4][2], Gl[4][2];
#pragma unroll
  for (int t = 0; t < 4; ++t) {
#pragma unroll
    for (int kk = 0; kk < 2; ++kk) {
      const int cj = 8 * kk + 2 * lk;
      float4 ga = gt4[cj * 64 + 16 * t + li];
      float4 gb = gt4[(cj + 1) * 64 + 16 * t + li];
      float g[8] = {ga.x, ga.y, ga.z, ga.w, gb.x, gb.y, gb.z, gb.w};
      bf16x8 hh, ll;
#pragma unroll
      for (int j = 0; j < 8; ++j) {
        ushort h = bf16_rne(g[j]);
        hh[j] = (short)h;
        ll[j] = (short)bf16_rne(g[j] - bf16_up(h));
      }
      Gh[t][kk] = hh;
      Gl[t][kk] = ll;
    }
  }

  const float x2 = aux[128 + lane];
  float xc0 = aux[lane * 2 + 0];
  float xc1 = aux[lane * 2 + 1];
  float c20 = aux[192] + aux[193] + aux[194] + aux[195];
  float c21 = aux[196] + aux[197] + aux[198] + aux[199];

  float a0 = 0.f, a1 = 0.f;
  const int cl = li & 1;  // cluster this lane's B-frag serves

#pragma unroll 1
  for (int t = 0; t < Q; ++t) {
    float d0 = fmaxf(x2 + c20 - 2.f * xc0, EPS_SQRT);
    float d1 = fmaxf(x2 + c21 - 2.f * xc1, EPS_SQRT);
    float t0 = __builtin_amdgcn_sqrtf(d0), t1 = __builtin_amdgcn_sqrtf(d1);
    float mn = fminf(t0, t1);
    float e0 = __expf(mn - t0), e1 = __expf(mn - t1);
    float inv = __builtin_amdgcn_rcpf(e0 + e1);
    a0 = e0 * inv;
    a1 = e1 * inv;
    if (t == Q - 1) break;

    // ---- a -> bf16-split SoA in LDS (4 ds_write_b16)
    {
      ushort h0 = bf16_rne(a0);
      ushort l0 = bf16_rne(a0 - bf16_up(h0));
      ushort h1 = bf16_rne(a1);
      ushort l1 = bf16_rne(a1 - bf16_up(h1));
      Ah[0][lane] = h0;
      Al[0][lane] = l0;
      Ah[1][lane] = h1;
      Al[1][lane] = l1;
    }
    // den on VALU pipe overlaps the LDS write latency
    float den0 = wave_total(a0);
    float den1 = wave_total(a1);
    wave_fence();  // order: a-writes before B-frag reads (1-wave block)

    // ---- B-fragments of a: col=li (cluster), k = kk*32+lk*8+j.
    bf16x8 bh[2], bl[2];
#pragma unroll
    for (int kk = 0; kk < 2; ++kk) {
      bh[kk] = *(const bf16x8*)&Ah[cl][kk * 32 + lk * 8];
      bl[kk] = *(const bf16x8*)&Al[cl][kk * 32 + lk * 8];
    }
    // ---- m = G.a : 24 MFMA (Gh*ah + Gh*al + Gl*ah)
    f32x4 acc[4] = {{0.f, 0.f, 0.f, 0.f},
                    {0.f, 0.f, 0.f, 0.f},
                    {0.f, 0.f, 0.f, 0.f},
                    {0.f, 0.f, 0.f, 0.f}};
#pragma unroll
    for (int tt = 0; tt < 4; ++tt) {
#pragma unroll
      for (int kk = 0; kk < 2; ++kk) {
        acc[tt] = __builtin_amdgcn_mfma_f32_16x16x32_bf16(Gh[tt][kk], bh[kk],
                                                          acc[tt], 0, 0, 0);
        acc[tt] = __builtin_amdgcn_mfma_f32_16x16x32_bf16(Gh[tt][kk], bl[kk],
                                                          acc[tt], 0, 0, 0);
        acc[tt] = __builtin_amdgcn_mfma_f32_16x16x32_bf16(Gl[tt][kk], bh[kk],
                                                          acc[tt], 0, 0, 0);
      }
    }
    // ---- C-frag (col=li=cluster, row=16t+lk*4+r) -> m_s (4 b128 writes)
    if (li < 2) {
#pragma unroll
      for (int tt = 0; tt < 4; ++tt)
        *(float4*)&m_s[li][16 * tt + lk * 4] =
            make_float4(acc[tt][0], acc[tt][1], acc[tt][2], acc[tt][3]);
    }
    wave_fence();  // order: m-writes before m reads (1-wave block)

    float m0 = m_s[0][lane];
    float m1 = m_s[1][lane];
    float s0 = wave_total(a0 * m0);  // = |num_0|^2
    float s1 = wave_total(a1 * m1);

    float i0 = __builtin_amdgcn_rcpf(den0 + EPS_DEN);
    float i1 = __builtin_amdgcn_rcpf(den1 + EPS_DEN);
    xc0 = m0 * i0;
    xc1 = m1 * i1;
    c20 = s0 * i0 * i0;
    c21 = s1 * i1 * i1;
  }

  // ---- epilogue: centers = (a^T hs)/(den+eps); write assignment
  *(float2*)&a_s[lane * 2] = make_float2(a0, a1);
  float den0 = wave_total(a0);
  float den1 = wave_total(a1);
  wave_fence();
  float i0 = __builtin_amdgcn_rcpf(den0 + EPS_DEN);
  float i1 = __builtin_amdgcn_rcpf(den1 + EPS_DEN);

  const float4* hb4 = (const float4*)(hs + (size_t)prob * Q * C);
  const float2* a2 = (const float2*)a_s;
  float4 n0 = make_float4(0.f, 0.f, 0.f, 0.f);
  float4 n1 = make_float4(0.f, 0.f, 0.f, 0.f);
#pragma unroll 8
  for (int q2 = 0; q2 < Q; ++q2) {
    float4 h = hb4[q2 * 64 + lane];
    float2 aq = a2[q2];
    n0.x = fmaf(aq.x, h.x, n0.x);
    n0.y = fmaf(aq.x, h.y, n0.y);
    n0.z = fmaf(aq.x, h.z, n0.z);
    n0.w = fmaf(aq.x, h.w, n0.w);
    n1.x = fmaf(aq.y, h.x, n1.x);
    n1.y = fmaf(aq.y, h.y, n1.y);
    n1.z = fmaf(aq.y, h.z, n1.z);
    n1.w = fmaf(aq.y, h.w, n1.w);
  }
  float4* outc4 = (float4*)(out + (size_t)prob * 2 * C);
  outc4[lane] = make_float4(n0.x * i0, n0.y * i0, n0.z * i0, n0.w * i0);
  outc4[64 + lane] = make_float4(n1.x * i1, n1.y * i1, n1.z * i1, n1.w * i1);

  float* outa = out + (size_t)PB * 2 * C + (size_t)prob * Q * 2;
  *(float2*)&outa[lane * 2] = make_float2(a0, a1);
}

extern "C" void kernel_launch(void* const* d_in, const int* in_sizes, int n_in,
                              void* d_out, int out_size, void* d_ws,
                              size_t ws_size, hipStream_t stream) {
  const float* hs = (const float*)d_in[0];
  const float* cen = (const float*)d_in[1];
  float* out = (float*)d_out;
  float* ws = (float*)d_ws;  // needs PB*(4096+256)*4 B ~= 26.8 MB
  hipLaunchKernelGGL(k1_gram, dim3(PB), dim3(256), 0, stream, hs, cen, ws);
  hipLaunchKernelGGL(k2_iter, dim3(PB), dim3(64), 0, stream, hs, ws, out);
}

// Round 10
// 81.144 us; speedup vs baseline: 1.3984x; 1.1100x over previous
//
#include <hip/hip_runtime.h>

namespace {
constexpr int PB = 6 * 256;  // 1536 independent (l,n) problems
constexpr int Q = 64;
constexpr int C = 256;
constexpr float EPS_DEN = 1e-7f;
constexpr float EPS_SQRT = 1e-12f;
constexpr int GT_FLOATS = Q * Q;  // 4096 per problem (transposed-packed)
constexpr int AUX_FLOATS = 256;   // xc0[64][2] | x2[64] | c2 partials[8]

typedef __attribute__((ext_vector_type(8))) short bf16x8;
typedef __attribute__((ext_vector_type(4))) float f32x4;

// DPP row rotate-add (VALU pipe). Proven R1/R5.
template <int CTRL>
__device__ __forceinline__ float ror_add(float v) {
  int r = __builtin_amdgcn_mov_dpp(__float_as_int(v), CTRL, 0xF, 0xF, true);
  return v + __int_as_float(r);
}

// Canonical GCN wave64 DPP reduction; all-lane result via readlane 63.
// Proven R5-R9 (passed).
__device__ __forceinline__ float wave_total(float v) {
  v = ror_add<0x121>(v);  // row_ror:1
  v = ror_add<0x122>(v);  // row_ror:2
  v = ror_add<0x124>(v);  // row_ror:4
  v = ror_add<0x128>(v);  // row_ror:8
  {
    int t = __builtin_amdgcn_update_dpp(0, __float_as_int(v), 0x142, 0xA, 0xF,
                                        true);  // ROW_BCAST15
    v = v + __int_as_float(t);
  }
  {
    int t = __builtin_amdgcn_update_dpp(0, __float_as_int(v), 0x143, 0xC, 0xF,
                                        true);  // ROW_BCAST31
    v = v + __int_as_float(t);
  }
  return __int_as_float(__builtin_amdgcn_readlane(__float_as_int(v), 63));
}

__device__ __forceinline__ ushort bf16_rne(float x) {
  uint u = __float_as_uint(x);
  return (ushort)((u + 0x7FFFu + ((u >> 16) & 1u)) >> 16);
}
__device__ __forceinline__ float bf16_up(ushort h) {
  return __uint_as_float((uint)h << 16);
}

// Compiler-only fence: keeps LDS write->read program order without s_barrier.
// Valid for SINGLE-WAVE blocks: the DS pipe processes a wave's ops in order.
__device__ __forceinline__ void wave_fence() { asm volatile("" ::: "memory"); }
}  // namespace

// -------- kernel 1: G = H H^T via bf16-split MFMA; x2=diag(G); xc0; c2_0
// __launch_bounds__(256,2): R6 showed (256,4) squeezes VGPR 124->64 and
// spills acc to scratch (+23 MB WRITE, 27->68 us). LDS caps blocks/CU anyway.
__global__ __launch_bounds__(256, 2) void k1_gram(
    const float* __restrict__ hs, const float* __restrict__ cen,
    float* __restrict__ ws) {
  const int prob = blockIdx.x;
  const int tid = threadIdx.x;
  const int lane = tid & 63, w = tid >> 6;
  const int li = lane & 15, lk = lane >> 4;

  __shared__ __align__(16) ushort Hh[64 * 128];  // bf16 hi plane (one C-half)
  __shared__ __align__(16) ushort Hl[64 * 128];  // bf16 lo plane
  __shared__ __align__(16) ushort Ch[2 * 256];   // cen hi (full C, linear)
  __shared__ __align__(16) ushort Cl[2 * 256];   // cen lo

  const float4* hsg4 = (const float4*)(hs + (size_t)prob * Q * C);
  float* gtp = ws + (size_t)prob * GT_FLOATS;
  float* aux = ws + (size_t)PB * GT_FLOATS + (size_t)prob * AUX_FLOATS;

  f32x4 acc[4] = {{0.f, 0.f, 0.f, 0.f},
                  {0.f, 0.f, 0.f, 0.f},
                  {0.f, 0.f, 0.f, 0.f},
                  {0.f, 0.f, 0.f, 0.f}};
  f32x4 accX = {0.f, 0.f, 0.f, 0.f};
  const int rA = 16 * w + li;
  const int swz = (li & 7) << 4;

#pragma unroll 1
  for (int half = 0; half < 2; ++half) {
#pragma unroll
    for (int i = 0; i < 8; ++i) {
      const int c = i * 256 + tid;  // 2048 chunks = 64 rows x 32 col4
      const int r = c >> 5, col4 = c & 31;
      float4 v = hsg4[r * 64 + half * 32 + col4];
      ushort h0 = bf16_rne(v.x), h1 = bf16_rne(v.y), h2 = bf16_rne(v.z),
             h3 = bf16_rne(v.w);
      ushort l0 = bf16_rne(v.x - bf16_up(h0));
      ushort l1 = bf16_rne(v.y - bf16_up(h1));
      ushort l2 = bf16_rne(v.z - bf16_up(h2));
      ushort l3 = bf16_rne(v.w - bf16_up(h3));
      const int boff = (col4 * 8) ^ ((r & 7) << 4);
      const int idx = r * 128 + (boff >> 1);
      *(ushort4*)&Hh[idx] = make_ushort4(h0, h1, h2, h3);
      *(ushort4*)&Hl[idx] = make_ushort4(l0, l1, l2, l3);
    }
    if (half == 0) {
      if (tid < 128) {
        const float4* cg4 = (const float4*)(cen + (size_t)prob * 2 * C);
        float4 v = cg4[tid];
        ushort h0 = bf16_rne(v.x), h1 = bf16_rne(v.y), h2 = bf16_rne(v.z),
               h3 = bf16_rne(v.w);
        ushort l0 = bf16_rne(v.x - bf16_up(h0));
        ushort l1 = bf16_rne(v.y - bf16_up(h1));
        ushort l2 = bf16_rne(v.z - bf16_up(h2));
        ushort l3 = bf16_rne(v.w - bf16_up(h3));
        const int idx = (tid >> 6) * 256 + (tid & 63) * 4;
        *(ushort4*)&Ch[idx] = make_ushort4(h0, h1, h2, h3);
        *(ushort4*)&Cl[idx] = make_ushort4(l0, l1, l2, l3);
      }
      float c0v = cen[(size_t)prob * 2 * C + tid];
      float c1v = cen[(size_t)prob * 2 * C + C + tid];
      float p0 = wave_total(c0v * c0v);
      float p1 = wave_total(c1v * c1v);
      if (lane == 0) {
        aux[192 + w] = p0;
        aux[196 + w] = p1;
      }
    }
    __syncthreads();

#pragma unroll
    for (int kk2 = 0; kk2 < 4; ++kk2) {
      const int kk = half * 4 + kk2;
      const int byteA = (kk2 * 64 + lk * 16) ^ swz;
      const int offA = byteA >> 1;
      bf16x8 ah = *(const bf16x8*)&Hh[rA * 128 + offA];
      bf16x8 al = *(const bf16x8*)&Hl[rA * 128 + offA];
      bf16x8 cbh = {0, 0, 0, 0, 0, 0, 0, 0};
      bf16x8 cbl = {0, 0, 0, 0, 0, 0, 0, 0};
      if (li < 2) {
        const int cidx = li * 256 + kk * 32 + lk * 8;
        cbh = *(const bf16x8*)&Ch[cidx];
        cbl = *(const bf16x8*)&Cl[cidx];
      }
      accX = __builtin_amdgcn_mfma_f32_16x16x32_bf16(ah, cbh, accX, 0, 0, 0);
      accX = __builtin_amdgcn_mfma_f32_16x16x32_bf16(ah, cbl, accX, 0, 0, 0);
      accX = __builtin_amdgcn_mfma_f32_16x16x32_bf16(al, cbh, accX, 0, 0, 0);
#pragma unroll
      for (int tj = 0; tj < 4; ++tj) {
        if (tj < w) continue;  // wave-uniform skip (symmetry)
        const int rB = 16 * tj + li;
        bf16x8 bh = *(const bf16x8*)&Hh[rB * 128 + offA];
        bf16x8 bl = *(const bf16x8*)&Hl[rB * 128 + offA];
        acc[tj] =
            __builtin_amdgcn_mfma_f32_16x16x32_bf16(ah, bh, acc[tj], 0, 0, 0);
        acc[tj] =
            __builtin_amdgcn_mfma_f32_16x16x32_bf16(ah, bl, acc[tj], 0, 0, 0);
        acc[tj] =
            __builtin_amdgcn_mfma_f32_16x16x32_bf16(al, bh, acc[tj], 0, 0, 0);
      }
    }
    __syncthreads();
  }

#pragma unroll
  for (int tj = 0; tj < 4; ++tj) {
    if (tj < w) continue;
#pragma unroll
    for (int r = 0; r < 4; ++r) {
      const float v = acc[tj][r];
      const int row = 16 * w + lk * 4 + r;
      const int col = 16 * tj + li;
      gtp[(col >> 2) * 256 + row * 4 + (col & 3)] = v;
      if (tj > w) gtp[(row >> 2) * 256 + col * 4 + (row & 3)] = v;
      if (row == col) aux[128 + row] = v;
    }
  }
  if (li < 2) {
#pragma unroll
    for (int r = 0; r < 4; ++r) {
      const int q = 16 * w + lk * 4 + r;
      aux[q * 2 + li] = accX[r];
    }
  }
}

// -------- kernel 2: 64 EM iterations, 1 wave/problem.
// R10: a as SINGLE bf16 plane (a in [0,1]; lo-plane term ~2^-10*|G|*den in m
// -> ~1e-3/iter in a, contracting) => 16 MFMA (4 chains of 4), 2 ds_write,
// 2 ds_read per iter. Softmax via direct exp(-t) (t<=~45, fp32-safe).
__global__ __launch_bounds__(64, 2) void k2_iter(const float* __restrict__ hs,
                                                 const float* __restrict__ ws,
                                                 float* __restrict__ out) {
  const int prob = blockIdx.x;
  const int lane = threadIdx.x;  // = q
  const int li = lane & 15, lk = lane >> 4;

  __shared__ __align__(16) ushort Ah[2][64];  // a bf16, SoA per cluster
  __shared__ __align__(16) float m_s[2][64];  // m = G.a, SoA per cluster
  __shared__ __align__(16) float a_s[2 * Q];  // final a (epilogue)

  const float4* gt4 = (const float4*)(ws + (size_t)prob * GT_FLOATS);
  const float* aux = ws + (size_t)PB * GT_FLOATS + (size_t)prob * AUX_FLOATS;

  // ---- G -> A-fragments (bf16 split), row = 16t+li, k = kk*32+lk*8+j.
  bf16x8 Gh[4][2], Gl[4][2];
#pragma unroll
  for (int t = 0; t < 4; ++t) {
#pragma unroll
    for (int kk = 0; kk < 2; ++kk) {
      const int cj = 8 * kk + 2 * lk;
      float4 ga = gt4[cj * 64 + 16 * t + li];
      float4 gb = gt4[(cj + 1) * 64 + 16 * t + li];
      float g[8] = {ga.x, ga.y, ga.z, ga.w, gb.x, gb.y, gb.z, gb.w};
      bf16x8 hh, ll;
#pragma unroll
      for (int j = 0; j < 8; ++j) {
        ushort h = bf16_rne(g[j]);
        hh[j] = (short)h;
        ll[j] = (short)bf16_rne(g[j] - bf16_up(h));
      }
      Gh[t][kk] = hh;
      Gl[t][kk] = ll;
    }
  }

  const float x2 = aux[128 + lane];
  float xc0 = aux[lane * 2 + 0];
  float xc1 = aux[lane * 2 + 1];
  float c20 = aux[192] + aux[193] + aux[194] + aux[195];
  float c21 = aux[196] + aux[197] + aux[198] + aux[199];

  float a0 = 0.f, a1 = 0.f;
  const int cl = li & 1;  // cluster this lane's B-frag serves

#pragma unroll 1
  for (int t = 0; t < Q; ++t) {
    float d0 = fmaxf(x2 + c20 - 2.f * xc0, EPS_SQRT);
    float d1 = fmaxf(x2 + c21 - 2.f * xc1, EPS_SQRT);
    float t0 = __builtin_amdgcn_sqrtf(d0), t1 = __builtin_amdgcn_sqrtf(d1);
    // direct softmax: t in [0,~45] so exp(-t) >= ~3e-20, fp32-normal; the
    // max-subtract is unnecessary and off the critical path.
    float e0 = __expf(-t0), e1 = __expf(-t1);
    float inv = __builtin_amdgcn_rcpf(e0 + e1);
    a0 = e0 * inv;
    a1 = e1 * inv;
    if (t == Q - 1) break;

    // ---- a -> bf16 SoA in LDS (2 ds_write_b16)
    Ah[0][lane] = bf16_rne(a0);
    Ah[1][lane] = bf16_rne(a1);
    // den on VALU pipe overlaps the LDS write latency
    float den0 = wave_total(a0);
    float den1 = wave_total(a1);
    wave_fence();  // order: a-writes before B-frag reads (1-wave block)

    // ---- B-fragment of a: col=li (cluster cl), k = kk*32+lk*8+j.
    bf16x8 bh[2];
#pragma unroll
    for (int kk = 0; kk < 2; ++kk)
      bh[kk] = *(const bf16x8*)&Ah[cl][kk * 32 + lk * 8];

    // ---- m = G.a : 16 MFMA, 4 independent chains of 4
    f32x4 acc[4] = {{0.f, 0.f, 0.f, 0.f},
                    {0.f, 0.f, 0.f, 0.f},
                    {0.f, 0.f, 0.f, 0.f},
                    {0.f, 0.f, 0.f, 0.f}};
#pragma unroll
    for (int tt = 0; tt < 4; ++tt) {
#pragma unroll
      for (int kk = 0; kk < 2; ++kk) {
        acc[tt] = __builtin_amdgcn_mfma_f32_16x16x32_bf16(Gh[tt][kk], bh[kk],
                                                          acc[tt], 0, 0, 0);
        acc[tt] = __builtin_amdgcn_mfma_f32_16x16x32_bf16(Gl[tt][kk], bh[kk],
                                                          acc[tt], 0, 0, 0);
      }
    }
    // ---- C-frag (col=li=cluster, row=16t+lk*4+r) -> m_s (4 b128 writes)
    if (li < 2) {
#pragma unroll
      for (int tt = 0; tt < 4; ++tt)
        *(float4*)&m_s[li][16 * tt + lk * 4] =
            make_float4(acc[tt][0], acc[tt][1], acc[tt][2], acc[tt][3]);
    }
    wave_fence();  // order: m-writes before m reads (1-wave block)

    float m0 = m_s[0][lane];
    float m1 = m_s[1][lane];
    float s0 = wave_total(a0 * m0);  // = |num_0|^2
    float s1 = wave_total(a1 * m1);

    float i0 = __builtin_amdgcn_rcpf(den0 + EPS_DEN);
    float i1 = __builtin_amdgcn_rcpf(den1 + EPS_DEN);
    xc0 = m0 * i0;
    xc1 = m1 * i1;
    c20 = s0 * i0 * i0;
    c21 = s1 * i1 * i1;
  }

  // ---- epilogue: centers = (a^T hs)/(den+eps); write assignment
  *(float2*)&a_s[lane * 2] = make_float2(a0, a1);
  float den0 = wave_total(a0);
  float den1 = wave_total(a1);
  wave_fence();
  float i0 = __builtin_amdgcn_rcpf(den0 + EPS_DEN);
  float i1 = __builtin_amdgcn_rcpf(den1 + EPS_DEN);

  const float4* hb4 = (const float4*)(hs + (size_t)prob * Q * C);
  const float2* a2 = (const float2*)a_s;
  float4 n0 = make_float4(0.f, 0.f, 0.f, 0.f);
  float4 n1 = make_float4(0.f, 0.f, 0.f, 0.f);
#pragma unroll 8
  for (int q2 = 0; q2 < Q; ++q2) {
    float4 h = hb4[q2 * 64 + lane];
    float2 aq = a2[q2];
    n0.x = fmaf(aq.x, h.x, n0.x);
    n0.y = fmaf(aq.x, h.y, n0.y);
    n0.z = fmaf(aq.x, h.z, n0.z);
    n0.w = fmaf(aq.x, h.w, n0.w);
    n1.x = fmaf(aq.y, h.x, n1.x);
    n1.y = fmaf(aq.y, h.y, n1.y);
    n1.z = fmaf(aq.y, h.z, n1.z);
    n1.w = fmaf(aq.y, h.w, n1.w);
  }
  float4* outc4 = (float4*)(out + (size_t)prob * 2 * C);
  outc4[lane] = make_float4(n0.x * i0, n0.y * i0, n0.z * i0, n0.w * i0);
  outc4[64 + lane] = make_float4(n1.x * i1, n1.y * i1, n1.z * i1, n1.w * i1);

  float* outa = out + (size_t)PB * 2 * C + (size_t)prob * Q * 2;
  *(float2*)&outa[lane * 2] = make_float2(a0, a1);
}

extern "C" void kernel_launch(void* const* d_in, const int* in_sizes, int n_in,
                              void* d_out, int out_size, void* d_ws,
                              size_t ws_size, hipStream_t stream) {
  const float* hs = (const float*)d_in[0];
  const float* cen = (const float*)d_in[1];
  float* out = (float*)d_out;
  float* ws = (float*)d_ws;  // needs PB*(4096+256)*4 B ~= 26.8 MB
  hipLaunchKernelGGL(k1_gram, dim3(PB), dim3(256), 0, stream, hs, cen, ws);
  hipLaunchKernelGGL(k2_iter, dim3(PB), dim3(64), 0, stream, hs, ws, out);
}